// Round 9
// baseline (506.559 us; speedup 1.0000x reference)
//
#include <hip/hip_runtime.h>
#include <math.h>

// x: (64,512,256) f32 -> 32768 tokens x 256 dims. codebook: (8192,256) f32.
#define N_TOK 32768
#define DDIM  256
#define KCB   8192
#define SLICES 4
#define KS     (KCB / SLICES)    // 2048 codes per slice
#define TCODES 32                // codes per LDS tile (3-buffer pipeline)
#define NSTEP  (KS / TCODES)     // 64 tiles per slice
#define NBUF   3                 // triple buffer -> prefetch depth 2
#define MARGIN 1.0f              // acc-scale gap guaranteeing exact winner
#define NFBLK  (N_TOK / 4)       // finalize blocks (1 token/wave, 4 waves)

typedef _Float16 half_t;
typedef half_t half8 __attribute__((ext_vector_type(8)));
typedef half_t half4 __attribute__((ext_vector_type(4)));
typedef float  f32x4  __attribute__((ext_vector_type(4)));
typedef float  f32x2  __attribute__((ext_vector_type(2)));
typedef float  f32x16 __attribute__((ext_vector_type(16)));

#define GLOBAL_AS __attribute__((address_space(1)))
#define LDS_AS    __attribute__((address_space(3)))

// ---------------------------------------------------------------------------
// P0: codebook f32 -> f16 copy + fp32 row norms.  (R0 verbatim)
__global__ __launch_bounds__(64) void prep_cb(const float* __restrict__ cb,
                                              half_t* __restrict__ cb16,
                                              float* __restrict__ cnorm) {
    int code = blockIdx.x;
    int lane = threadIdx.x;
    f32x4 v = *(const f32x4*)(cb + (size_t)code * DDIM + lane * 4);
    half4 h; h[0]=(half_t)v[0]; h[1]=(half_t)v[1]; h[2]=(half_t)v[2]; h[3]=(half_t)v[3];
    *(half4*)(cb16 + (size_t)code * DDIM + lane * 4) = h;
    float s = v[0]*v[0] + v[1]*v[1] + v[2]*v[2] + v[3]*v[3];
    #pragma unroll
    for (int off = 32; off > 0; off >>= 1) s += __shfl_down(s, off);
    if (lane == 0) cnorm[code] = s;
}

// load 8 consecutive f32, convert to 8 f16 (prologue only)
__device__ __forceinline__ half8 ldcvt8(const float* __restrict__ p) {
    f32x4 a = *(const f32x4*)p;
    f32x4 b = *(const f32x4*)(p + 4);
    half8 h;
    h[0]=(half_t)a[0]; h[1]=(half_t)a[1]; h[2]=(half_t)a[2]; h[3]=(half_t)a[3];
    h[4]=(half_t)b[0]; h[5]=(half_t)b[1]; h[6]=(half_t)b[2]; h[7]=(half_t)b[3];
    return h;
}

// pack: f32 key with low 13 mantissa bits replaced by code id (sortable)
__device__ __forceinline__ float packkey(float a, unsigned code) {
    return __uint_as_float((__float_as_uint(a) & 0xFFFFE000u) | code);
}

// ---------------------------------------------------------------------------
// Pass A: 256 threads (4 waves), 64 tokens/wave, one 2048-code K-slice.
// R8 structure (depth-2 triple-buffer, counted vmcnt, same STAGE swizzle)
// but the MFMA is 32x32x16: 32 MFMA/tile @32.3cyc/SIMD = 1034 cyc matrix-
// pipe demand vs 16x16's 1242 (-17%), 4x fewer MFMA issue slots, same LDS
// traffic and same epilogue op count.  Fragment mapping (HW-verified family):
//   A: row = lane&31 (token), k = (lane>>5)*8 + j   -> afrag[rt][ks], 128 r
//   B: col = lane&31 (code),  k = (lane>>5)*8 + j   -> one ds_read_b128/ks
//   C: col = lane&31, row = (reg&3) + 8*(reg>>2) + 4*(lane>>5)
// Each lane owns ONE code column -> per-lane code id; trackers k0/k1[2][16].
__global__ __launch_bounds__(256, 2)
void passA(const float* __restrict__ x, const half_t* __restrict__ cb16,
           const float* __restrict__ cnorm, float* __restrict__ cand) {

    __shared__ __align__(16) half_t buf[NBUF][TCODES * 256];   // 3 x 16 KB
    __shared__ __align__(16) float  cn_lds[KS];                // 8 KB

    const int tid  = threadIdx.x;
    const int w    = tid >> 6;
    const int lane = tid & 63;
    const int col  = lane & 31;        // code column / token row (A)
    const int hi   = lane >> 5;        // k-half
    const int tokBase   = blockIdx.x * 256 + w * 64;   // wave's 64 tokens
    const int codeBase0 = blockIdx.y * KS;

    // ---- A fragments: afrag[rt][ks] = x[tokBase+rt*32+col][ks*16+hi*8 ..+7]
    half8 afrag[2][16];
    #pragma unroll
    for (int rt = 0; rt < 2; rt++) {
        const float* xr = x + (size_t)(tokBase + rt * 32 + col) * DDIM + hi * 8;
        #pragma unroll
        for (int ks = 0; ks < 16; ks++)
            afrag[rt][ks] = ldcvt8(xr + ks * 16);
    }

    // packed top-2 keys (max semantics) per (rt, reg)
    float k0[2][16], k1[2][16];
    #pragma unroll
    for (int rt = 0; rt < 2; rt++)
        #pragma unroll
        for (int r = 0; r < 16; r++) { k0[rt][r] = -INFINITY; k1[rt][r] = -INFINITY; }

    // B-read address pieces: row = col, chunk = (ks*2+hi) ^ (col&7)
    const int rbase = col * 256;       // half_t offset of code row
    const int sx    = col & 7;

    // stage 16 KB tile nt into buffer slot si (async, swizzled to match
    // read side): 1024 x 16B chunks, 4/thread.  (R8 verbatim)
    const char*   cbbase  = (const char*)(cb16 + (size_t)codeBase0 * DDIM);
    half_t* const bufbase = &buf[0][0];
    #define STAGE(nt, si)                                                       \
        {                                                                       \
            const char* srcb = cbbase + (size_t)(nt) * (TCODES * 512);          \
            half_t* dstb = bufbase + (si) * (TCODES * 256);                     \
            _Pragma("unroll")                                                   \
            for (int o = 0; o < 4; o++) {                                       \
                int L = o * 256 + tid;                                          \
                int r = L >> 5, c = (L & 31) ^ (r & 7);                         \
                __builtin_amdgcn_global_load_lds(                               \
                    (const GLOBAL_AS void*)(srcb + r * 512 + c * 16),           \
                    (LDS_AS void*)(dstb + (o * 256 + w * 64) * 8), 16, 0, 0);   \
            }                                                                   \
        }

    // one-time cnorm slice -> LDS (8 x 4B per thread, drains with prologue)
    {
        const float* cnsrc = cnorm + codeBase0;
        #pragma unroll
        for (int o = 0; o < 8; o++)
            __builtin_amdgcn_global_load_lds(
                (const GLOBAL_AS void*)(cnsrc + o * 256 + w * 64 + lane),
                (LDS_AS void*)&cn_lds[o * 256 + w * 64], 4, 0, 0);
    }
    STAGE(0, 0)
    STAGE(1, 1)
    asm volatile("s_waitcnt vmcnt(0)" ::: "memory");   // prologue drain (only one)
    __builtin_amdgcn_s_barrier();

    int cc = 0;   // compute slot
    int sc = 2;   // stage slot

    for (int nt = 0; nt < NSTEP; nt++) {
        if (nt + 2 < NSTEP) {
            STAGE(nt + 2, sc)
            asm volatile("s_waitcnt vmcnt(8)" ::: "memory");
        } else if (nt + 1 < NSTEP) {
            asm volatile("s_waitcnt vmcnt(4)" ::: "memory");
        } else {
            asm volatile("s_waitcnt vmcnt(0)" ::: "memory");
        }
        __builtin_amdgcn_s_barrier();       // B1: tile nt resident for all waves

        const half_t* cur = bufbase + cc * (TCODES * 256);

        const float mc = -0.5f * cn_lds[nt * TCODES + col];
        f32x16 acc[2];
        #pragma unroll
        for (int rt = 0; rt < 2; rt++)
            #pragma unroll
            for (int r = 0; r < 16; r++) acc[rt][r] = mc;

        __builtin_amdgcn_s_setprio(1);
        #pragma unroll
        for (int ks = 0; ks < 16; ks++) {
            half8 bf = *(const half8*)(cur + rbase + (((ks * 2 + hi) ^ sx) * 8));
            acc[0] = __builtin_amdgcn_mfma_f32_32x32x16_f16(afrag[0][ks], bf, acc[0], 0, 0, 0);
            acc[1] = __builtin_amdgcn_mfma_f32_32x32x16_f16(afrag[1][ks], bf, acc[1], 0, 0, 0);
        }
        __builtin_amdgcn_s_setprio(0);

        const unsigned codev = (unsigned)(codeBase0 + nt * TCODES + col);
        #pragma unroll
        for (int rt = 0; rt < 2; rt++)
            #pragma unroll
            for (int r = 0; r < 16; r++) {
                float a = packkey(acc[rt][r], codev);
                k1[rt][r] = __builtin_amdgcn_fmed3f(k0[rt][r], a, k1[rt][r]);
                k0[rt][r] = fmaxf(k0[rt][r], a);
            }
        __builtin_amdgcn_s_barrier();       // B2: reads of buf[cc] done
        cc = (cc == NBUF - 1) ? 0 : cc + 1;
        sc = (sc == NBUF - 1) ? 0 : sc + 1;
    }

    // ---- merge top-2 across the 32 code lanes (per 32-lane half) ----------
    #pragma unroll
    for (int s = 1; s < 32; s <<= 1) {
        #pragma unroll
        for (int rt = 0; rt < 2; rt++)
            #pragma unroll
            for (int r = 0; r < 16; r++) {
                float o0 = __shfl_xor(k0[rt][r], s, 64);
                float o1 = __shfl_xor(k1[rt][r], s, 64);
                float n1 = fmaxf(fminf(k0[rt][r], o0), fmaxf(k1[rt][r], o1));
                k0[rt][r] = fmaxf(k0[rt][r], o0);
                k1[rt][r] = n1;
            }
    }
    if (col == 0) {                        // lanes 0 and 32 write
        #pragma unroll
        for (int rt = 0; rt < 2; rt++)
            #pragma unroll
            for (int r = 0; r < 16; r++) {
                int token = tokBase + rt * 32 + (r & 3) + 8 * (r >> 2) + 4 * hi;
                f32x2 kk; kk[0] = k0[rt][r]; kk[1] = k1[rt][r];
                *(f32x2*)&cand[(size_t)token * (SLICES * 2) + blockIdx.y * 2] = kk;
            }
    }
}

// ---------------------------------------------------------------------------
// K2: 1 token/wave (R0 verbatim) + fused loss reduction: last-arriver block
// (R6-validated release/acquire ticket) sums the 8192 partials.
__global__ __launch_bounds__(256) void finalize_kernel(
    const float* __restrict__ x, const float* __restrict__ cb,
    const float* __restrict__ cnorm, const float* __restrict__ cand,
    float* __restrict__ out, float* __restrict__ partials,
    unsigned* __restrict__ ticket) {

    const int tid = threadIdx.x, w = tid >> 6, lane = tid & 63;
    const int token = blockIdx.x * 4 + w;
    const float* xrow = x + (size_t)token * DDIM;

    f32x4 ka = *(const f32x4*)(cand + (size_t)token * 8);
    f32x4 kb = *(const f32x4*)(cand + (size_t)token * 8 + 4);
    float v[8] = {ka[0], ka[1], ka[2], ka[3], kb[0], kb[1], kb[2], kb[3]};
    float t0 = -INFINITY, t1 = -INFINITY;
    #pragma unroll
    for (int j = 0; j < 8; j++) {
        float m = fminf(t0, v[j]);
        t0 = fmaxf(t0, v[j]);
        t1 = fmaxf(t1, m);
    }
    int bidx = (int)(__float_as_uint(t0) & 0x1FFFu);

    if (!(t0 - t1 > MARGIN)) {
        const int j = lane >> 3, sub = lane & 7;
        int cj = (int)(__float_as_uint(v[j]) & 0x1FFFu);
        const float* crow = cb + (size_t)cj * DDIM;
        float p = 0.0f;
        #pragma unroll
        for (int c = 0; c < 8; c++) {
            f32x4 xa = *(const f32x4*)(xrow + c * 32 + sub * 4);
            f32x4 ca = *(const f32x4*)(crow + c * 32 + sub * 4);
            p += xa[0]*ca[0] + xa[1]*ca[1] + xa[2]*ca[2] + xa[3]*ca[3];
        }
        p += __shfl_xor(p, 1, 64);
        p += __shfl_xor(p, 2, 64);
        p += __shfl_xor(p, 4, 64);
        float bd = cnorm[cj] - 2.0f * p;
        int   bi = cj;
        #pragma unroll
        for (int s = 8; s < 64; s <<= 1) {   // reference tie-break: lower index
            float od = __shfl_xor(bd, s, 64);
            int   oi = __shfl_xor(bi, s, 64);
            if (od < bd || (od == bd && oi < bi)) { bd = od; bi = oi; }
        }
        bidx = bi;
    }

    f32x4 cv = *(const f32x4*)(cb + (size_t)bidx * DDIM + lane * 4);
    f32x4 xv = *(const f32x4*)(xrow + lane * 4);
    *(f32x4*)(out + (size_t)token * DDIM + lane * 4) = cv;
    float d0 = cv[0]-xv[0], d1 = cv[1]-xv[1], d2 = cv[2]-xv[2], d3 = cv[3]-xv[3];
    float lsum = d0*d0 + d1*d1 + d2*d2 + d3*d3;

    __shared__ float red[256];
    __shared__ int   flag;
    red[tid] = lsum;
    __syncthreads();
    #pragma unroll
    for (int s = 128; s > 0; s >>= 1) {
        if (tid < s) red[tid] += red[tid + s];
        __syncthreads();
    }
    if (tid == 0) partials[blockIdx.x] = red[0];

    // ---- last-arriver reduces the loss (replaces the reduce_loss dispatch)
    __syncthreads();
    if (tid == 0) {
        __threadfence();             // release: partials visible device-wide
        flag = (atomicAdd(ticket, 1u) == (unsigned)(NFBLK - 1));
    }
    __syncthreads();
    if (!flag) return;
    __threadfence();                 // acquire
    float s = 0.0f;
    #pragma unroll
    for (int i = 0; i < 8; i++) {    // 256 thr x 8 x f32x4 = 8192 floats
        f32x4 pv = *(const f32x4*)(partials + (size_t)(i * 256 + tid) * 4);
        s += pv[0] + pv[1] + pv[2] + pv[3];
    }
    red[tid] = s;
    __syncthreads();
    #pragma unroll
    for (int st = 128; st > 0; st >>= 1) {
        if (tid < st) red[tid] += red[tid + st];
        __syncthreads();
    }
    if (tid == 0)
        out[(size_t)N_TOK * DDIM] = red[0] * (0.25f / (float)((size_t)N_TOK * DDIM));
}

// ---------------------------------------------------------------------------
extern "C" void kernel_launch(void* const* d_in, const int* in_sizes, int n_in,
                              void* d_out, int out_size, void* d_ws, size_t ws_size,
                              hipStream_t stream) {
    const float* x  = (const float*)d_in[0];
    const float* cb = (const float*)d_in[1];
    float* out = (float*)d_out;

    // ws: cb16 (4 MB f16) | cnorm[8192] | cand[32768*8] | partials[8192] | ticket
    half_t*   cb16     = (half_t*)d_ws;
    float*    cnorm    = (float*)(cb16 + (size_t)KCB * DDIM);
    float*    cand     = cnorm + KCB;
    float*    partials = cand + (size_t)N_TOK * 8;
    unsigned* ticket   = (unsigned*)(partials + NFBLK);

    hipMemsetAsync(ticket, 0, sizeof(unsigned), stream);
    prep_cb<<<KCB, 64, 0, stream>>>(cb, cb16, cnorm);
    dim3 gA(N_TOK / 256, SLICES);
    passA<<<gA, 256, 0, stream>>>(x, cb16, cnorm, cand);
    finalize_kernel<<<NFBLK, 256, 0, stream>>>(x, cb, cnorm, cand, out,
                                               partials, ticket);
}

// Round 10
// 307.366 us; speedup vs baseline: 1.6481x; 1.6481x over previous
//
#include <hip/hip_runtime.h>
#include <math.h>

// x: (64,512,256) f32 -> 32768 tokens x 256 dims. codebook: (8192,256) f32.
#define N_TOK 32768
#define DDIM  256
#define KCB   8192
#define SLICES 4
#define KS     (KCB / SLICES)    // 2048 codes per slice
#define TCODES 32                // codes per LDS tile (3-buffer pipeline)
#define NSTEP  (KS / TCODES)     // 64 tiles per slice
#define NBUF   3                 // triple buffer -> prefetch depth 2
#define MARGIN 1.0f              // acc-scale gap guaranteeing exact winner
#define NFBLK  (N_TOK / 4)       // finalize blocks (1 token/wave, 4 waves)
#define NLSLOT 64                // loss accumulator slots (contention /64)

typedef _Float16 half_t;
typedef half_t half8 __attribute__((ext_vector_type(8)));
typedef half_t half4 __attribute__((ext_vector_type(4)));
typedef float  f32x4 __attribute__((ext_vector_type(4)));
typedef float  f32x2 __attribute__((ext_vector_type(2)));

#define GLOBAL_AS __attribute__((address_space(1)))
#define LDS_AS    __attribute__((address_space(3)))

// ---------------------------------------------------------------------------
// P0: codebook f32 -> f16 copy + fp32 row norms.  (R0 verbatim)
__global__ __launch_bounds__(64) void prep_cb(const float* __restrict__ cb,
                                              half_t* __restrict__ cb16,
                                              float* __restrict__ cnorm) {
    int code = blockIdx.x;
    int lane = threadIdx.x;
    f32x4 v = *(const f32x4*)(cb + (size_t)code * DDIM + lane * 4);
    half4 h; h[0]=(half_t)v[0]; h[1]=(half_t)v[1]; h[2]=(half_t)v[2]; h[3]=(half_t)v[3];
    *(half4*)(cb16 + (size_t)code * DDIM + lane * 4) = h;
    float s = v[0]*v[0] + v[1]*v[1] + v[2]*v[2] + v[3]*v[3];
    #pragma unroll
    for (int off = 32; off > 0; off >>= 1) s += __shfl_down(s, off);
    if (lane == 0) cnorm[code] = s;
}

// load 8 consecutive f32, convert to 8 f16 (prologue only)
__device__ __forceinline__ half8 ldcvt8(const float* __restrict__ p) {
    f32x4 a = *(const f32x4*)p;
    f32x4 b = *(const f32x4*)(p + 4);
    half8 h;
    h[0]=(half_t)a[0]; h[1]=(half_t)a[1]; h[2]=(half_t)a[2]; h[3]=(half_t)a[3];
    h[4]=(half_t)b[0]; h[5]=(half_t)b[1]; h[6]=(half_t)b[2]; h[7]=(half_t)b[3];
    return h;
}

// pack: f32 key with low 13 mantissa bits replaced by code id (sortable)
__device__ __forceinline__ float packkey(float a, unsigned code) {
    return __uint_as_float((__float_as_uint(a) & 0xFFFFE000u) | code);
}

// ---------------------------------------------------------------------------
// Pass A: R8 VERBATIM (best measured 133 us).  256 threads (4 waves),
// 64 tokens/wave, one 2048-code K-slice; 3 x 16KB tile buffers, prefetch
// depth 2 with counted vmcnt; 16x16x32 f16 MFMA.
__global__ __launch_bounds__(256, 2)
void passA(const float* __restrict__ x, const half_t* __restrict__ cb16,
           const float* __restrict__ cnorm, float* __restrict__ cand) {

    __shared__ __align__(16) half_t buf[NBUF][TCODES * 256];   // 3 x 16 KB
    __shared__ __align__(16) float  cn_lds[KS];                // 8 KB

    const int tid  = threadIdx.x;
    const int w    = tid >> 6;
    const int lane = tid & 63;
    const int quad = lane >> 4;
    const int mcol = lane & 15;
    const int tokBase   = blockIdx.x * 256 + w * 64;   // wave's 64 tokens
    const int codeBase0 = blockIdx.y * KS;

    // ---- A fragments: A[m=mcol][k=quad*8+j], full D=256 in regs (128 regs)
    half8 afrag[4][8];
    #pragma unroll
    for (int rt = 0; rt < 4; rt++) {
        const float* xr = x + (size_t)(tokBase + rt * 16 + mcol) * DDIM + quad * 8;
        #pragma unroll
        for (int dk = 0; dk < 8; dk++)
            afrag[rt][dk] = ldcvt8(xr + dk * 32);
    }

    // ---- B-read LDS offsets: row = mcol, chunk = (dk*4+quad)^(mcol&7)
    int boff[8];
    #pragma unroll
    for (int dk = 0; dk < 8; dk++)
        boff[dk] = mcol * 256 + (((dk * 4 + quad) ^ (mcol & 7)) * 8);

    // packed top-2 keys (max semantics) per owned token [rt][r]
    float k0[4][4], k1[4][4];
    #pragma unroll
    for (int rt = 0; rt < 4; rt++)
        #pragma unroll
        for (int r = 0; r < 4; r++) { k0[rt][r] = -INFINITY; k1[rt][r] = -INFINITY; }

    // stage 16 KB tile nt into buffer slot si (async, swizzled to match
    // read side): 1024 x 16B chunks, 4/thread.
    const char*   cbbase  = (const char*)(cb16 + (size_t)codeBase0 * DDIM);
    half_t* const bufbase = &buf[0][0];
    #define STAGE(nt, si)                                                       \
        {                                                                       \
            const char* srcb = cbbase + (size_t)(nt) * (TCODES * 512);          \
            half_t* dstb = bufbase + (si) * (TCODES * 256);                     \
            _Pragma("unroll")                                                   \
            for (int o = 0; o < 4; o++) {                                       \
                int L = o * 256 + tid;                                          \
                int r = L >> 5, c = (L & 31) ^ (r & 7);                         \
                __builtin_amdgcn_global_load_lds(                               \
                    (const GLOBAL_AS void*)(srcb + r * 512 + c * 16),           \
                    (LDS_AS void*)(dstb + (o * 256 + w * 64) * 8), 16, 0, 0);   \
            }                                                                   \
        }

    // one-time cnorm slice -> LDS (8 x 4B per thread, drains with prologue)
    {
        const float* cnsrc = cnorm + codeBase0;
        #pragma unroll
        for (int o = 0; o < 8; o++)
            __builtin_amdgcn_global_load_lds(
                (const GLOBAL_AS void*)(cnsrc + o * 256 + w * 64 + lane),
                (LDS_AS void*)&cn_lds[o * 256 + w * 64], 4, 0, 0);
    }
    STAGE(0, 0)
    STAGE(1, 1)
    asm volatile("s_waitcnt vmcnt(0)" ::: "memory");   // prologue drain (only one)
    __builtin_amdgcn_s_barrier();

    int cc = 0;   // compute slot = nt % 3
    int sc = 2;   // stage slot   = (nt+2) % 3

    for (int nt = 0; nt < NSTEP; nt++) {
        // depth-2 prefetch: issue tile nt+2, wait so tile nt is resident.
        if (nt + 2 < NSTEP) {
            STAGE(nt + 2, sc)
            asm volatile("s_waitcnt vmcnt(8)" ::: "memory");
        } else if (nt + 1 < NSTEP) {
            asm volatile("s_waitcnt vmcnt(4)" ::: "memory");
        } else {
            asm volatile("s_waitcnt vmcnt(0)" ::: "memory");
        }
        __builtin_amdgcn_s_barrier();       // B1: tile nt resident for all waves

        const half_t* cur = bufbase + cc * (TCODES * 256);

        const float mc0 = -0.5f * cn_lds[nt * TCODES + mcol];
        const float mc1 = -0.5f * cn_lds[nt * TCODES + 16 + mcol];
        f32x4 acc[2][4];                    // [ct][rt]
        #pragma unroll
        for (int rt = 0; rt < 4; rt++) {
            acc[0][rt][0]=mc0; acc[0][rt][1]=mc0; acc[0][rt][2]=mc0; acc[0][rt][3]=mc0;
            acc[1][rt][0]=mc1; acc[1][rt][1]=mc1; acc[1][rt][2]=mc1; acc[1][rt][3]=mc1;
        }
        const half_t* crow0 = cur;
        const half_t* crow1 = cur + 16 * 256;
        __builtin_amdgcn_s_setprio(1);
        #pragma unroll
        for (int dk = 0; dk < 8; dk++) {
            half8 bf0 = *(const half8*)(crow0 + boff[dk]);
            half8 bf1 = *(const half8*)(crow1 + boff[dk]);
            #pragma unroll
            for (int rt = 0; rt < 4; rt++) {
                acc[0][rt] = __builtin_amdgcn_mfma_f32_16x16x32_f16(afrag[rt][dk], bf0, acc[0][rt], 0, 0, 0);
                acc[1][rt] = __builtin_amdgcn_mfma_f32_16x16x32_f16(afrag[rt][dk], bf1, acc[1][rt], 0, 0, 0);
            }
        }
        __builtin_amdgcn_s_setprio(0);
        // C layout: col = lane&15 (code), row = quad*4 + r (token).
        const unsigned code0 = (unsigned)(codeBase0 + nt * TCODES + mcol);
        const unsigned code1 = code0 + 16;
        #pragma unroll
        for (int rt = 0; rt < 4; rt++)
            #pragma unroll
            for (int r = 0; r < 4; r++) {
                float a = packkey(acc[0][rt][r], code0);
                float b = packkey(acc[1][rt][r], code1);
                k1[rt][r] = fmaxf(k1[rt][r], __builtin_amdgcn_fmed3f(k0[rt][r], a, b));
                k0[rt][r] = fmaxf(fmaxf(k0[rt][r], a), b);
            }
        __builtin_amdgcn_s_barrier();       // B2: reads of buf[cc] done
        cc = (cc == NBUF - 1) ? 0 : cc + 1;
        sc = (sc == NBUF - 1) ? 0 : sc + 1;
    }

    // ---- merge top-2 (max) across the 16 class lanes; lane mcol==0 writes.
    #pragma unroll
    for (int s = 1; s < 16; s <<= 1) {
        #pragma unroll
        for (int rt = 0; rt < 4; rt++)
            #pragma unroll
            for (int r = 0; r < 4; r++) {
                float o0 = __shfl_xor(k0[rt][r], s, 64);
                float o1 = __shfl_xor(k1[rt][r], s, 64);
                float n1 = fmaxf(fminf(k0[rt][r], o0), fmaxf(k1[rt][r], o1));
                k0[rt][r] = fmaxf(k0[rt][r], o0);
                k1[rt][r] = n1;
            }
    }
    if (mcol == 0) {
        #pragma unroll
        for (int rt = 0; rt < 4; rt++)
            #pragma unroll
            for (int r = 0; r < 4; r++) {
                int token = tokBase + rt * 16 + quad * 4 + r;
                f32x2 kk; kk[0] = k0[rt][r]; kk[1] = k1[rt][r];
                *(f32x2*)&cand[(size_t)token * (SLICES * 2) + blockIdx.y * 2] = kk;
            }
    }
}

// ---------------------------------------------------------------------------
// K2: 1 token/wave (R0 core) + loss via device-scope ATOMICS (no fence --
// R9's per-block __threadfence was an L2 writeback x8192 = 270us).  Each
// block atomicAdds its partial into lossacc[blockIdx&64), orders it with a
// local vmcnt drain (atomics count in vmcnt), bumps the ticket; the
// last-arriver sums the 64 slots with agent-scope atomic loads and writes
// the scalar.  Atomic ops are L2-point coherent (m20: device scope).
__global__ __launch_bounds__(256) void finalize_kernel(
    const float* __restrict__ x, const float* __restrict__ cb,
    const float* __restrict__ cnorm, const float* __restrict__ cand,
    float* __restrict__ out, float* __restrict__ lossacc,
    unsigned* __restrict__ ticket) {

    const int tid = threadIdx.x, w = tid >> 6, lane = tid & 63;
    const int token = blockIdx.x * 4 + w;
    const float* xrow = x + (size_t)token * DDIM;

    f32x4 ka = *(const f32x4*)(cand + (size_t)token * 8);
    f32x4 kb = *(const f32x4*)(cand + (size_t)token * 8 + 4);
    float v[8] = {ka[0], ka[1], ka[2], ka[3], kb[0], kb[1], kb[2], kb[3]};
    float t0 = -INFINITY, t1 = -INFINITY;
    #pragma unroll
    for (int j = 0; j < 8; j++) {
        float m = fminf(t0, v[j]);
        t0 = fmaxf(t0, v[j]);
        t1 = fmaxf(t1, m);
    }
    int bidx = (int)(__float_as_uint(t0) & 0x1FFFu);

    if (!(t0 - t1 > MARGIN)) {
        const int j = lane >> 3, sub = lane & 7;
        int cj = (int)(__float_as_uint(v[j]) & 0x1FFFu);
        const float* crow = cb + (size_t)cj * DDIM;
        float p = 0.0f;
        #pragma unroll
        for (int c = 0; c < 8; c++) {
            f32x4 xa = *(const f32x4*)(xrow + c * 32 + sub * 4);
            f32x4 ca = *(const f32x4*)(crow + c * 32 + sub * 4);
            p += xa[0]*ca[0] + xa[1]*ca[1] + xa[2]*ca[2] + xa[3]*ca[3];
        }
        p += __shfl_xor(p, 1, 64);
        p += __shfl_xor(p, 2, 64);
        p += __shfl_xor(p, 4, 64);
        float bd = cnorm[cj] - 2.0f * p;
        int   bi = cj;
        #pragma unroll
        for (int s = 8; s < 64; s <<= 1) {   // reference tie-break: lower index
            float od = __shfl_xor(bd, s, 64);
            int   oi = __shfl_xor(bi, s, 64);
            if (od < bd || (od == bd && oi < bi)) { bd = od; bi = oi; }
        }
        bidx = bi;
    }

    f32x4 cv = *(const f32x4*)(cb + (size_t)bidx * DDIM + lane * 4);
    f32x4 xv = *(const f32x4*)(xrow + lane * 4);
    *(f32x4*)(out + (size_t)token * DDIM + lane * 4) = cv;
    float d0 = cv[0]-xv[0], d1 = cv[1]-xv[1], d2 = cv[2]-xv[2], d3 = cv[3]-xv[3];
    float lsum = d0*d0 + d1*d1 + d2*d2 + d3*d3;

    __shared__ float red[256];
    __shared__ int   flag;
    red[tid] = lsum;
    __syncthreads();
    #pragma unroll
    for (int s = 128; s > 0; s >>= 1) {
        if (tid < s) red[tid] += red[tid + s];
        __syncthreads();
    }
    if (tid == 0) {
        atomicAdd(&lossacc[blockIdx.x & (NLSLOT - 1)], red[0]);
        asm volatile("s_waitcnt vmcnt(0)" ::: "memory");   // loss-add complete
        flag = (atomicAdd(ticket, 1u) == (unsigned)(NFBLK - 1));
    }
    __syncthreads();
    if (!flag) return;

    // last-arriver: all 8191 other loss-adds are complete at the L2 atomic
    // point (each preceded its ticket add).  Sum the 64 slots coherently.
    float s = (tid < NLSLOT)
                  ? __hip_atomic_load(&lossacc[tid], __ATOMIC_RELAXED,
                                      __HIP_MEMORY_SCOPE_AGENT)
                  : 0.0f;
    #pragma unroll
    for (int st = 1; st < 64; st <<= 1) s += __shfl_xor(s, st, 64);
    if (tid == 0)
        out[(size_t)N_TOK * DDIM] = s * (0.25f / (float)((size_t)N_TOK * DDIM));
}

// ---------------------------------------------------------------------------
extern "C" void kernel_launch(void* const* d_in, const int* in_sizes, int n_in,
                              void* d_out, int out_size, void* d_ws, size_t ws_size,
                              hipStream_t stream) {
    const float* x  = (const float*)d_in[0];
    const float* cb = (const float*)d_in[1];
    float* out = (float*)d_out;

    // ws: cb16 (4 MB f16) | cnorm[8192] | cand[32768*8] | lossacc[64] | ticket
    half_t*   cb16     = (half_t*)d_ws;
    float*    cnorm    = (float*)(cb16 + (size_t)KCB * DDIM);
    float*    cand     = cnorm + KCB;
    float*    lossacc  = cand + (size_t)N_TOK * 8;
    unsigned* ticket   = (unsigned*)(lossacc + NLSLOT);

    hipMemsetAsync(lossacc, 0, (NLSLOT + 1) * sizeof(float), stream);
    prep_cb<<<KCB, 64, 0, stream>>>(cb, cb16, cnorm);
    dim3 gA(N_TOK / 256, SLICES);
    passA<<<gA, 256, 0, stream>>>(x, cb16, cnorm, cand);
    finalize_kernel<<<NFBLK, 256, 0, stream>>>(x, cb, cnorm, cand, out,
                                               lossacc, ticket);
}

// Round 11
// 221.838 us; speedup vs baseline: 2.2835x; 1.3855x over previous
//
#include <hip/hip_runtime.h>
#include <math.h>

// x: (64,512,256) f32 -> 32768 tokens x 256 dims. codebook: (8192,256) f32.
#define N_TOK 32768
#define DDIM  256
#define KCB   8192
#define SLICES 4
#define KS     (KCB / SLICES)    // 2048 codes per slice
#define TCODES 32                // codes per LDS tile (3-buffer pipeline)
#define NSTEP  (KS / TCODES)     // 64 tiles per slice
#define NBUF   3                 // triple buffer -> prefetch depth 2
#define MARGIN 1.0f              // acc-scale gap guaranteeing exact winner
#define NFBLK  (N_TOK / 4)       // finalize blocks (1 token/wave, 4 waves)

typedef _Float16 half_t;
typedef half_t half8 __attribute__((ext_vector_type(8)));
typedef half_t half4 __attribute__((ext_vector_type(4)));
typedef float  f32x4 __attribute__((ext_vector_type(4)));
typedef float  f32x2 __attribute__((ext_vector_type(2)));

#define GLOBAL_AS __attribute__((address_space(1)))
#define LDS_AS    __attribute__((address_space(3)))

// ---------------------------------------------------------------------------
// P0: codebook f32 -> f16 copy + fp32 row norms.  (R0 verbatim)
__global__ __launch_bounds__(64) void prep_cb(const float* __restrict__ cb,
                                              half_t* __restrict__ cb16,
                                              float* __restrict__ cnorm) {
    int code = blockIdx.x;
    int lane = threadIdx.x;
    f32x4 v = *(const f32x4*)(cb + (size_t)code * DDIM + lane * 4);
    half4 h; h[0]=(half_t)v[0]; h[1]=(half_t)v[1]; h[2]=(half_t)v[2]; h[3]=(half_t)v[3];
    *(half4*)(cb16 + (size_t)code * DDIM + lane * 4) = h;
    float s = v[0]*v[0] + v[1]*v[1] + v[2]*v[2] + v[3]*v[3];
    #pragma unroll
    for (int off = 32; off > 0; off >>= 1) s += __shfl_down(s, off);
    if (lane == 0) cnorm[code] = s;
}

// load 8 consecutive f32, convert to 8 f16 (prologue only)
__device__ __forceinline__ half8 ldcvt8(const float* __restrict__ p) {
    f32x4 a = *(const f32x4*)p;
    f32x4 b = *(const f32x4*)(p + 4);
    half8 h;
    h[0]=(half_t)a[0]; h[1]=(half_t)a[1]; h[2]=(half_t)a[2]; h[3]=(half_t)a[3];
    h[4]=(half_t)b[0]; h[5]=(half_t)b[1]; h[6]=(half_t)b[2]; h[7]=(half_t)b[3];
    return h;
}

// pack: f32 key with low 13 mantissa bits replaced by code id (sortable)
__device__ __forceinline__ float packkey(float a, unsigned code) {
    return __uint_as_float((__float_as_uint(a) & 0xFFFFE000u) | code);
}

// ---------------------------------------------------------------------------
// Pass A: R8 base (best measured 133us: depth-2 triple buffer, counted
// vmcnt, 16x16x32 MFMA) + ONE change: the per-tile compute is split into
// 4 phases {reg-prefetch next 4 B-frags || 16 MFMA || s_barrier(q<3)}.
// Rationale (T3/T5 regime gate): setprio is null in a lockstep 2-phase
// schedule (R0-R10: MfmaUtil pinned 44%); intra-tile barriers create wave
// role diversity (at each barrier some waves issue ds_reads while others
// enter MFMA) so the CU scheduler + setprio can overlap LDS/VALU phases of
// sibling waves with MFMA.  Barriers are only ADDED (buf lifetime B1..B2
// unchanged, uniform control flow) -> correctness-neutral.
__global__ __launch_bounds__(256, 2)
void passA(const float* __restrict__ x, const half_t* __restrict__ cb16,
           const float* __restrict__ cnorm, float* __restrict__ cand) {

    __shared__ __align__(16) half_t buf[NBUF][TCODES * 256];   // 3 x 16 KB
    __shared__ __align__(16) float  cn_lds[KS];                // 8 KB

    const int tid  = threadIdx.x;
    const int w    = tid >> 6;
    const int lane = tid & 63;
    const int quad = lane >> 4;
    const int mcol = lane & 15;
    const int tokBase   = blockIdx.x * 256 + w * 64;   // wave's 64 tokens
    const int codeBase0 = blockIdx.y * KS;

    // ---- A fragments: A[m=mcol][k=quad*8+j], full D=256 in regs (128 regs)
    half8 afrag[4][8];
    #pragma unroll
    for (int rt = 0; rt < 4; rt++) {
        const float* xr = x + (size_t)(tokBase + rt * 16 + mcol) * DDIM + quad * 8;
        #pragma unroll
        for (int dk = 0; dk < 8; dk++)
            afrag[rt][dk] = ldcvt8(xr + dk * 32);
    }

    // ---- B-read LDS offsets: row = mcol, chunk = (dk*4+quad)^(mcol&7)
    int boff[8];
    #pragma unroll
    for (int dk = 0; dk < 8; dk++)
        boff[dk] = mcol * 256 + (((dk * 4 + quad) ^ (mcol & 7)) * 8);

    // packed top-2 keys (max semantics) per owned token [rt][r]
    float k0[4][4], k1[4][4];
    #pragma unroll
    for (int rt = 0; rt < 4; rt++)
        #pragma unroll
        for (int r = 0; r < 4; r++) { k0[rt][r] = -INFINITY; k1[rt][r] = -INFINITY; }

    // stage 16 KB tile nt into buffer slot si (async, swizzled to match
    // read side): 1024 x 16B chunks, 4/thread.  (R8 verbatim)
    const char*   cbbase  = (const char*)(cb16 + (size_t)codeBase0 * DDIM);
    half_t* const bufbase = &buf[0][0];
    #define STAGE(nt, si)                                                       \
        {                                                                       \
            const char* srcb = cbbase + (size_t)(nt) * (TCODES * 512);          \
            half_t* dstb = bufbase + (si) * (TCODES * 256);                     \
            _Pragma("unroll")                                                   \
            for (int o = 0; o < 4; o++) {                                       \
                int L = o * 256 + tid;                                          \
                int r = L >> 5, c = (L & 31) ^ (r & 7);                         \
                __builtin_amdgcn_global_load_lds(                               \
                    (const GLOBAL_AS void*)(srcb + r * 512 + c * 16),           \
                    (LDS_AS void*)(dstb + (o * 256 + w * 64) * 8), 16, 0, 0);   \
            }                                                                   \
        }

    // one-time cnorm slice -> LDS (8 x 4B per thread, drains with prologue)
    {
        const float* cnsrc = cnorm + codeBase0;
        #pragma unroll
        for (int o = 0; o < 8; o++)
            __builtin_amdgcn_global_load_lds(
                (const GLOBAL_AS void*)(cnsrc + o * 256 + w * 64 + lane),
                (LDS_AS void*)&cn_lds[o * 256 + w * 64], 4, 0, 0);
    }
    STAGE(0, 0)
    STAGE(1, 1)
    asm volatile("s_waitcnt vmcnt(0)" ::: "memory");   // prologue drain (only one)
    __builtin_amdgcn_s_barrier();

    int cc = 0;   // compute slot = nt % 3
    int sc = 2;   // stage slot   = (nt+2) % 3

    for (int nt = 0; nt < NSTEP; nt++) {
        // depth-2 prefetch: issue tile nt+2, wait so tile nt is resident.
        if (nt + 2 < NSTEP) {
            STAGE(nt + 2, sc)
            asm volatile("s_waitcnt vmcnt(8)" ::: "memory");
        } else if (nt + 1 < NSTEP) {
            asm volatile("s_waitcnt vmcnt(4)" ::: "memory");
        } else {
            asm volatile("s_waitcnt vmcnt(0)" ::: "memory");
        }
        __builtin_amdgcn_s_barrier();       // B1: tile nt resident for all waves

        const half_t* cur = bufbase + cc * (TCODES * 256);

        const float mc0 = -0.5f * cn_lds[nt * TCODES + mcol];
        const float mc1 = -0.5f * cn_lds[nt * TCODES + 16 + mcol];
        f32x4 acc[2][4];                    // [ct][rt]
        #pragma unroll
        for (int rt = 0; rt < 4; rt++) {
            acc[0][rt][0]=mc0; acc[0][rt][1]=mc0; acc[0][rt][2]=mc0; acc[0][rt][3]=mc0;
            acc[1][rt][0]=mc1; acc[1][rt][1]=mc1; acc[1][rt][2]=mc1; acc[1][rt][3]=mc1;
        }
        const half_t* crow0 = cur;
        const half_t* crow1 = cur + 16 * 256;

        // ---- 4-phase compute: prefetch dk-pair q+1 into named regs while
        // ---- MFMAing pair q; s_barrier between phases (q<3) = role split.
        half8 nb0 = *(const half8*)(crow0 + boff[0]);
        half8 nb1 = *(const half8*)(crow1 + boff[0]);
        half8 nb2 = *(const half8*)(crow0 + boff[1]);
        half8 nb3 = *(const half8*)(crow1 + boff[1]);
        #pragma unroll
        for (int q = 0; q < 4; q++) {
            half8 c0 = nb0, c1 = nb1, c2 = nb2, c3 = nb3;
            if (q < 3) {
                nb0 = *(const half8*)(crow0 + boff[2 * q + 2]);
                nb1 = *(const half8*)(crow1 + boff[2 * q + 2]);
                nb2 = *(const half8*)(crow0 + boff[2 * q + 3]);
                nb3 = *(const half8*)(crow1 + boff[2 * q + 3]);
            }
            __builtin_amdgcn_s_setprio(1);
            #pragma unroll
            for (int rt = 0; rt < 4; rt++) {
                acc[0][rt] = __builtin_amdgcn_mfma_f32_16x16x32_f16(afrag[rt][2 * q],     c0, acc[0][rt], 0, 0, 0);
                acc[1][rt] = __builtin_amdgcn_mfma_f32_16x16x32_f16(afrag[rt][2 * q],     c1, acc[1][rt], 0, 0, 0);
            }
            #pragma unroll
            for (int rt = 0; rt < 4; rt++) {
                acc[0][rt] = __builtin_amdgcn_mfma_f32_16x16x32_f16(afrag[rt][2 * q + 1], c2, acc[0][rt], 0, 0, 0);
                acc[1][rt] = __builtin_amdgcn_mfma_f32_16x16x32_f16(afrag[rt][2 * q + 1], c3, acc[1][rt], 0, 0, 0);
            }
            __builtin_amdgcn_s_setprio(0);
            if (q < 3) __builtin_amdgcn_s_barrier();   // intra-tile role split
        }

        // C layout: col = lane&15 (code), row = quad*4 + r (token).
        const unsigned code0 = (unsigned)(codeBase0 + nt * TCODES + mcol);
        const unsigned code1 = code0 + 16;
        #pragma unroll
        for (int rt = 0; rt < 4; rt++)
            #pragma unroll
            for (int r = 0; r < 4; r++) {
                float a = packkey(acc[0][rt][r], code0);
                float b = packkey(acc[1][rt][r], code1);
                k1[rt][r] = fmaxf(k1[rt][r], __builtin_amdgcn_fmed3f(k0[rt][r], a, b));
                k0[rt][r] = fmaxf(fmaxf(k0[rt][r], a), b);
            }
        __builtin_amdgcn_s_barrier();       // B2: reads of buf[cc] done
        cc = (cc == NBUF - 1) ? 0 : cc + 1;
        sc = (sc == NBUF - 1) ? 0 : sc + 1;
    }

    // ---- merge top-2 (max) across the 16 class lanes; lane mcol==0 writes.
    #pragma unroll
    for (int s = 1; s < 16; s <<= 1) {
        #pragma unroll
        for (int rt = 0; rt < 4; rt++)
            #pragma unroll
            for (int r = 0; r < 4; r++) {
                float o0 = __shfl_xor(k0[rt][r], s, 64);
                float o1 = __shfl_xor(k1[rt][r], s, 64);
                float n1 = fmaxf(fminf(k0[rt][r], o0), fmaxf(k1[rt][r], o1));
                k0[rt][r] = fmaxf(k0[rt][r], o0);
                k1[rt][r] = n1;
            }
    }
    if (mcol == 0) {
        #pragma unroll
        for (int rt = 0; rt < 4; rt++)
            #pragma unroll
            for (int r = 0; r < 4; r++) {
                int token = tokBase + rt * 16 + quad * 4 + r;
                f32x2 kk; kk[0] = k0[rt][r]; kk[1] = k1[rt][r];
                *(f32x2*)&cand[(size_t)token * (SLICES * 2) + blockIdx.y * 2] = kk;
            }
    }
}

// ---------------------------------------------------------------------------
// K2: 1 token/wave.  (R0 verbatim -- the 4-dispatch tail is the proven
// optimum; every cross-block fusion attempt (R6/R7/R9/R10) regressed.)
__global__ __launch_bounds__(256) void finalize_kernel(
    const float* __restrict__ x, const float* __restrict__ cb,
    const float* __restrict__ cnorm, const float* __restrict__ cand,
    float* __restrict__ out, float* __restrict__ partials) {

    const int tid = threadIdx.x, w = tid >> 6, lane = tid & 63;
    const int token = blockIdx.x * 4 + w;
    const float* xrow = x + (size_t)token * DDIM;

    f32x4 ka = *(const f32x4*)(cand + (size_t)token * 8);
    f32x4 kb = *(const f32x4*)(cand + (size_t)token * 8 + 4);
    float v[8] = {ka[0], ka[1], ka[2], ka[3], kb[0], kb[1], kb[2], kb[3]};
    float t0 = -INFINITY, t1 = -INFINITY;
    #pragma unroll
    for (int j = 0; j < 8; j++) {
        float m = fminf(t0, v[j]);
        t0 = fmaxf(t0, v[j]);
        t1 = fmaxf(t1, m);
    }
    int bidx = (int)(__float_as_uint(t0) & 0x1FFFu);

    if (!(t0 - t1 > MARGIN)) {
        const int j = lane >> 3, sub = lane & 7;
        int cj = (int)(__float_as_uint(v[j]) & 0x1FFFu);
        const float* crow = cb + (size_t)cj * DDIM;
        float p = 0.0f;
        #pragma unroll
        for (int c = 0; c < 8; c++) {
            f32x4 xa = *(const f32x4*)(xrow + c * 32 + sub * 4);
            f32x4 ca = *(const f32x4*)(crow + c * 32 + sub * 4);
            p += xa[0]*ca[0] + xa[1]*ca[1] + xa[2]*ca[2] + xa[3]*ca[3];
        }
        p += __shfl_xor(p, 1, 64);
        p += __shfl_xor(p, 2, 64);
        p += __shfl_xor(p, 4, 64);
        float bd = cnorm[cj] - 2.0f * p;
        int   bi = cj;
        #pragma unroll
        for (int s = 8; s < 64; s <<= 1) {   // reference tie-break: lower index
            float od = __shfl_xor(bd, s, 64);
            int   oi = __shfl_xor(bi, s, 64);
            if (od < bd || (od == bd && oi < bi)) { bd = od; bi = oi; }
        }
        bidx = bi;
    }

    f32x4 cv = *(const f32x4*)(cb + (size_t)bidx * DDIM + lane * 4);
    f32x4 xv = *(const f32x4*)(xrow + lane * 4);
    *(f32x4*)(out + (size_t)token * DDIM + lane * 4) = cv;
    float d0 = cv[0]-xv[0], d1 = cv[1]-xv[1], d2 = cv[2]-xv[2], d3 = cv[3]-xv[3];
    float lsum = d0*d0 + d1*d1 + d2*d2 + d3*d3;

    __shared__ float red[256];
    red[tid] = lsum;
    __syncthreads();
    #pragma unroll
    for (int s = 128; s > 0; s >>= 1) {
        if (tid < s) red[tid] += red[tid + s];
        __syncthreads();
    }
    if (tid == 0) partials[blockIdx.x] = red[0];
}

// ---------------------------------------------------------------------------
// K3: single-block sum of the 8192 per-block loss partials.  (R0 verbatim)
__global__ __launch_bounds__(256) void reduce_loss(const float* __restrict__ partials,
                                                   float* __restrict__ out) {
    const int tid = threadIdx.x;
    float s = 0.0f;
    #pragma unroll
    for (int i = 0; i < 8; i++) {
        f32x4 v = *(const f32x4*)(partials + (size_t)(i * 256 + tid) * 4);
        s += v[0] + v[1] + v[2] + v[3];
    }
    __shared__ float red[256];
    red[tid] = s;
    __syncthreads();
    #pragma unroll
    for (int st = 128; st > 0; st >>= 1) {
        if (tid < st) red[tid] += red[tid + st];
        __syncthreads();
    }
    if (tid == 0)
        out[(size_t)N_TOK * DDIM] = red[0] * (0.25f / (float)((size_t)N_TOK * DDIM));
}

// ---------------------------------------------------------------------------
extern "C" void kernel_launch(void* const* d_in, const int* in_sizes, int n_in,
                              void* d_out, int out_size, void* d_ws, size_t ws_size,
                              hipStream_t stream) {
    const float* x  = (const float*)d_in[0];
    const float* cb = (const float*)d_in[1];
    float* out = (float*)d_out;

    // ws: cb16 (4 MB f16) | cnorm[8192] | cand[32768*8] | partials[8192]
    half_t* cb16     = (half_t*)d_ws;
    float*  cnorm    = (float*)(cb16 + (size_t)KCB * DDIM);
    float*  cand     = cnorm + KCB;
    float*  partials = cand + (size_t)N_TOK * 8;

    prep_cb<<<KCB, 64, 0, stream>>>(cb, cb16, cnorm);
    dim3 gA(N_TOK / 256, SLICES);
    passA<<<gA, 256, 0, stream>>>(x, cb16, cnorm, cand);
    finalize_kernel<<<NFBLK, 256, 0, stream>>>(x, cb, cnorm, cand, out, partials);
    reduce_loss<<<1, 256, 0, stream>>>(partials, out);
}

// Round 12
// 216.745 us; speedup vs baseline: 2.3371x; 1.0235x over previous
//
#include <hip/hip_runtime.h>
#include <math.h>

// x: (64,512,256) f32 -> 32768 tokens x 256 dims. codebook: (8192,256) f32.
#define N_TOK 32768
#define DDIM  256
#define KCB   8192
#define SLICES 4
#define KS     (KCB / SLICES)    // 2048 codes per slice
#define TCODES 32                // codes per LDS tile (3-buffer pipeline)
#define NSTEP  (KS / TCODES)     // 64 tiles per slice
#define NBUF   3                 // triple buffer -> prefetch depth 2
#define MARGIN 1.0f              // acc-scale gap guaranteeing exact winner
#define NFBLK  (N_TOK / 4)       // finalize blocks (1 token/wave, 4 waves)

typedef _Float16 half_t;
typedef half_t half8 __attribute__((ext_vector_type(8)));
typedef half_t half4 __attribute__((ext_vector_type(4)));
typedef float  f32x4 __attribute__((ext_vector_type(4)));
typedef float  f32x2 __attribute__((ext_vector_type(2)));

#define GLOBAL_AS __attribute__((address_space(1)))
#define LDS_AS    __attribute__((address_space(3)))

// ---------------------------------------------------------------------------
// P0: codebook f32 -> f16 copy + fp32 row norms.  (R0 verbatim)
__global__ __launch_bounds__(64) void prep_cb(const float* __restrict__ cb,
                                              half_t* __restrict__ cb16,
                                              float* __restrict__ cnorm) {
    int code = blockIdx.x;
    int lane = threadIdx.x;
    f32x4 v = *(const f32x4*)(cb + (size_t)code * DDIM + lane * 4);
    half4 h; h[0]=(half_t)v[0]; h[1]=(half_t)v[1]; h[2]=(half_t)v[2]; h[3]=(half_t)v[3];
    *(half4*)(cb16 + (size_t)code * DDIM + lane * 4) = h;
    float s = v[0]*v[0] + v[1]*v[1] + v[2]*v[2] + v[3]*v[3];
    #pragma unroll
    for (int off = 32; off > 0; off >>= 1) s += __shfl_down(s, off);
    if (lane == 0) cnorm[code] = s;
}

// load 8 consecutive f32, convert to 8 f16 (prologue only)
__device__ __forceinline__ half8 ldcvt8(const float* __restrict__ p) {
    f32x4 a = *(const f32x4*)p;
    f32x4 b = *(const f32x4*)(p + 4);
    half8 h;
    h[0]=(half_t)a[0]; h[1]=(half_t)a[1]; h[2]=(half_t)a[2]; h[3]=(half_t)a[3];
    h[4]=(half_t)b[0]; h[5]=(half_t)b[1]; h[6]=(half_t)b[2]; h[7]=(half_t)b[3];
    return h;
}

// pack via single v_bfi_b32: (mask & code) | (~mask & acc); mask in SGPR.
// (validated in R2/R4 runs)
__device__ __forceinline__ float packkey2(unsigned mask, unsigned code, float a) {
    float r;
    asm("v_bfi_b32 %0, %1, %2, %3" : "=v"(r) : "s"(mask), "v"(code), "v"(a));
    return r;
}
__device__ __forceinline__ float max3f(float a, float b, float c) {
    float r;
    asm("v_max3_f32 %0, %1, %2, %3" : "=v"(r) : "v"(a), "v"(b), "v"(c));
    return r;
}

// ---------------------------------------------------------------------------
// Pass A: R11 winner (128.4us: depth-2 triple buffer, counted vmcnt,
// 16x16x32 MFMA, 4-phase intra-tile role split) + ONE change: the top-2
// tracker epilogue is cut from 8 to 5 VALU ops per (rt,r) pair --
// v_bfi pack (1 op vs and+or), v_max3 for k0, code ids as incrementing
// VGPRs.  The epilogue is the exposed serial segment after each MFMA
// cluster (acc-dependent, barrier-bounded), so shortening it attacks the
// remaining MfmaUtil hole directly.
__global__ __launch_bounds__(256, 2)
void passA(const float* __restrict__ x, const half_t* __restrict__ cb16,
           const float* __restrict__ cnorm, float* __restrict__ cand) {

    __shared__ __align__(16) half_t buf[NBUF][TCODES * 256];   // 3 x 16 KB
    __shared__ __align__(16) float  cn_lds[KS];                // 8 KB

    const int tid  = threadIdx.x;
    const int w    = tid >> 6;
    const int lane = tid & 63;
    const int quad = lane >> 4;
    const int mcol = lane & 15;
    const int tokBase   = blockIdx.x * 256 + w * 64;   // wave's 64 tokens
    const int codeBase0 = blockIdx.y * KS;

    // ---- A fragments: A[m=mcol][k=quad*8+j], full D=256 in regs (128 regs)
    half8 afrag[4][8];
    #pragma unroll
    for (int rt = 0; rt < 4; rt++) {
        const float* xr = x + (size_t)(tokBase + rt * 16 + mcol) * DDIM + quad * 8;
        #pragma unroll
        for (int dk = 0; dk < 8; dk++)
            afrag[rt][dk] = ldcvt8(xr + dk * 32);
    }

    // ---- B-read LDS offsets: row = mcol, chunk = (dk*4+quad)^(mcol&7)
    int boff[8];
    #pragma unroll
    for (int dk = 0; dk < 8; dk++)
        boff[dk] = mcol * 256 + (((dk * 4 + quad) ^ (mcol & 7)) * 8);

    // packed top-2 keys (max semantics) per owned token [rt][r]
    float k0[4][4], k1[4][4];
    #pragma unroll
    for (int rt = 0; rt < 4; rt++)
        #pragma unroll
        for (int r = 0; r < 4; r++) { k0[rt][r] = -INFINITY; k1[rt][r] = -INFINITY; }

    // stage 16 KB tile nt into buffer slot si (async, swizzled to match
    // read side): 1024 x 16B chunks, 4/thread.  (R8 verbatim)
    const char*   cbbase  = (const char*)(cb16 + (size_t)codeBase0 * DDIM);
    half_t* const bufbase = &buf[0][0];
    #define STAGE(nt, si)                                                       \
        {                                                                       \
            const char* srcb = cbbase + (size_t)(nt) * (TCODES * 512);          \
            half_t* dstb = bufbase + (si) * (TCODES * 256);                     \
            _Pragma("unroll")                                                   \
            for (int o = 0; o < 4; o++) {                                       \
                int L = o * 256 + tid;                                          \
                int r = L >> 5, c = (L & 31) ^ (r & 7);                         \
                __builtin_amdgcn_global_load_lds(                               \
                    (const GLOBAL_AS void*)(srcb + r * 512 + c * 16),           \
                    (LDS_AS void*)(dstb + (o * 256 + w * 64) * 8), 16, 0, 0);   \
            }                                                                   \
        }

    // one-time cnorm slice -> LDS (8 x 4B per thread, drains with prologue)
    {
        const float* cnsrc = cnorm + codeBase0;
        #pragma unroll
        for (int o = 0; o < 8; o++)
            __builtin_amdgcn_global_load_lds(
                (const GLOBAL_AS void*)(cnsrc + o * 256 + w * 64 + lane),
                (LDS_AS void*)&cn_lds[o * 256 + w * 64], 4, 0, 0);
    }
    STAGE(0, 0)
    STAGE(1, 1)
    asm volatile("s_waitcnt vmcnt(0)" ::: "memory");   // prologue drain (only one)
    __builtin_amdgcn_s_barrier();

    int cc = 0;   // compute slot = nt % 3
    int sc = 2;   // stage slot   = (nt+2) % 3

    const unsigned kmask = 0x1FFFu;
    unsigned code0v = (unsigned)(codeBase0 + mcol);
    unsigned code1v = code0v + 16;

    for (int nt = 0; nt < NSTEP; nt++) {
        // depth-2 prefetch: issue tile nt+2, wait so tile nt is resident.
        if (nt + 2 < NSTEP) {
            STAGE(nt + 2, sc)
            asm volatile("s_waitcnt vmcnt(8)" ::: "memory");
        } else if (nt + 1 < NSTEP) {
            asm volatile("s_waitcnt vmcnt(4)" ::: "memory");
        } else {
            asm volatile("s_waitcnt vmcnt(0)" ::: "memory");
        }
        __builtin_amdgcn_s_barrier();       // B1: tile nt resident for all waves

        const half_t* cur = bufbase + cc * (TCODES * 256);

        const float mc0 = -0.5f * cn_lds[nt * TCODES + mcol];
        const float mc1 = -0.5f * cn_lds[nt * TCODES + 16 + mcol];
        f32x4 acc[2][4];                    // [ct][rt]
        #pragma unroll
        for (int rt = 0; rt < 4; rt++) {
            acc[0][rt][0]=mc0; acc[0][rt][1]=mc0; acc[0][rt][2]=mc0; acc[0][rt][3]=mc0;
            acc[1][rt][0]=mc1; acc[1][rt][1]=mc1; acc[1][rt][2]=mc1; acc[1][rt][3]=mc1;
        }
        const half_t* crow0 = cur;
        const half_t* crow1 = cur + 16 * 256;

        // ---- 4-phase compute: prefetch dk-pair q+1 into named regs while
        // ---- MFMAing pair q; s_barrier between phases (q<3) = role split.
        half8 nb0 = *(const half8*)(crow0 + boff[0]);
        half8 nb1 = *(const half8*)(crow1 + boff[0]);
        half8 nb2 = *(const half8*)(crow0 + boff[1]);
        half8 nb3 = *(const half8*)(crow1 + boff[1]);
        #pragma unroll
        for (int q = 0; q < 4; q++) {
            half8 c0 = nb0, c1 = nb1, c2 = nb2, c3 = nb3;
            if (q < 3) {
                nb0 = *(const half8*)(crow0 + boff[2 * q + 2]);
                nb1 = *(const half8*)(crow1 + boff[2 * q + 2]);
                nb2 = *(const half8*)(crow0 + boff[2 * q + 3]);
                nb3 = *(const half8*)(crow1 + boff[2 * q + 3]);
            }
            __builtin_amdgcn_s_setprio(1);
            #pragma unroll
            for (int rt = 0; rt < 4; rt++) {
                acc[0][rt] = __builtin_amdgcn_mfma_f32_16x16x32_f16(afrag[rt][2 * q],     c0, acc[0][rt], 0, 0, 0);
                acc[1][rt] = __builtin_amdgcn_mfma_f32_16x16x32_f16(afrag[rt][2 * q],     c1, acc[1][rt], 0, 0, 0);
            }
            #pragma unroll
            for (int rt = 0; rt < 4; rt++) {
                acc[0][rt] = __builtin_amdgcn_mfma_f32_16x16x32_f16(afrag[rt][2 * q + 1], c2, acc[0][rt], 0, 0, 0);
                acc[1][rt] = __builtin_amdgcn_mfma_f32_16x16x32_f16(afrag[rt][2 * q + 1], c3, acc[1][rt], 0, 0, 0);
            }
            __builtin_amdgcn_s_setprio(0);
            if (q < 3) __builtin_amdgcn_s_barrier();   // intra-tile role split
        }

        // C layout: col = lane&15 (code), row = quad*4 + r (token).
        // top-2 update, 5 VALU/pair: bfi, bfi, med3, max, max3.
        #pragma unroll
        for (int rt = 0; rt < 4; rt++)
            #pragma unroll
            for (int r = 0; r < 4; r++) {
                float a = packkey2(kmask, code0v, acc[0][rt][r]);
                float b = packkey2(kmask, code1v, acc[1][rt][r]);
                k1[rt][r] = fmaxf(k1[rt][r], __builtin_amdgcn_fmed3f(k0[rt][r], a, b));
                k0[rt][r] = max3f(k0[rt][r], a, b);
            }
        code0v += TCODES;
        code1v += TCODES;
        __builtin_amdgcn_s_barrier();       // B2: reads of buf[cc] done
        cc = (cc == NBUF - 1) ? 0 : cc + 1;
        sc = (sc == NBUF - 1) ? 0 : sc + 1;
    }

    // ---- merge top-2 (max) across the 16 class lanes; lane mcol==0 writes.
    #pragma unroll
    for (int s = 1; s < 16; s <<= 1) {
        #pragma unroll
        for (int rt = 0; rt < 4; rt++)
            #pragma unroll
            for (int r = 0; r < 4; r++) {
                float o0 = __shfl_xor(k0[rt][r], s, 64);
                float o1 = __shfl_xor(k1[rt][r], s, 64);
                float n1 = fmaxf(fminf(k0[rt][r], o0), fmaxf(k1[rt][r], o1));
                k0[rt][r] = fmaxf(k0[rt][r], o0);
                k1[rt][r] = n1;
            }
    }
    if (mcol == 0) {
        #pragma unroll
        for (int rt = 0; rt < 4; rt++)
            #pragma unroll
            for (int r = 0; r < 4; r++) {
                int token = tokBase + rt * 16 + quad * 4 + r;
                f32x2 kk; kk[0] = k0[rt][r]; kk[1] = k1[rt][r];
                *(f32x2*)&cand[(size_t)token * (SLICES * 2) + blockIdx.y * 2] = kk;
            }
    }
}

// ---------------------------------------------------------------------------
// K2: 1 token/wave.  (R0 verbatim -- the 4-dispatch tail is the proven
// optimum; every cross-block fusion attempt (R6/R7/R9/R10) regressed.)
__global__ __launch_bounds__(256) void finalize_kernel(
    const float* __restrict__ x, const float* __restrict__ cb,
    const float* __restrict__ cnorm, const float* __restrict__ cand,
    float* __restrict__ out, float* __restrict__ partials) {

    const int tid = threadIdx.x, w = tid >> 6, lane = tid & 63;
    const int token = blockIdx.x * 4 + w;
    const float* xrow = x + (size_t)token * DDIM;

    f32x4 ka = *(const f32x4*)(cand + (size_t)token * 8);
    f32x4 kb = *(const f32x4*)(cand + (size_t)token * 8 + 4);
    float v[8] = {ka[0], ka[1], ka[2], ka[3], kb[0], kb[1], kb[2], kb[3]};
    float t0 = -INFINITY, t1 = -INFINITY;
    #pragma unroll
    for (int j = 0; j < 8; j++) {
        float m = fminf(t0, v[j]);
        t0 = fmaxf(t0, v[j]);
        t1 = fmaxf(t1, m);
    }
    int bidx = (int)(__float_as_uint(t0) & 0x1FFFu);

    if (!(t0 - t1 > MARGIN)) {
        const int j = lane >> 3, sub = lane & 7;
        int cj = (int)(__float_as_uint(v[j]) & 0x1FFFu);
        const float* crow = cb + (size_t)cj * DDIM;
        float p = 0.0f;
        #pragma unroll
        for (int c = 0; c < 8; c++) {
            f32x4 xa = *(const f32x4*)(xrow + c * 32 + sub * 4);
            f32x4 ca = *(const f32x4*)(crow + c * 32 + sub * 4);
            p += xa[0]*ca[0] + xa[1]*ca[1] + xa[2]*ca[2] + xa[3]*ca[3];
        }
        p += __shfl_xor(p, 1, 64);
        p += __shfl_xor(p, 2, 64);
        p += __shfl_xor(p, 4, 64);
        float bd = cnorm[cj] - 2.0f * p;
        int   bi = cj;
        #pragma unroll
        for (int s = 8; s < 64; s <<= 1) {   // reference tie-break: lower index
            float od = __shfl_xor(bd, s, 64);
            int   oi = __shfl_xor(bi, s, 64);
            if (od < bd || (od == bd && oi < bi)) { bd = od; bi = oi; }
        }
        bidx = bi;
    }

    f32x4 cv = *(const f32x4*)(cb + (size_t)bidx * DDIM + lane * 4);
    f32x4 xv = *(const f32x4*)(xrow + lane * 4);
    *(f32x4*)(out + (size_t)token * DDIM + lane * 4) = cv;
    float d0 = cv[0]-xv[0], d1 = cv[1]-xv[1], d2 = cv[2]-xv[2], d3 = cv[3]-xv[3];
    float lsum = d0*d0 + d1*d1 + d2*d2 + d3*d3;

    __shared__ float red[256];
    red[tid] = lsum;
    __syncthreads();
    #pragma unroll
    for (int s = 128; s > 0; s >>= 1) {
        if (tid < s) red[tid] += red[tid + s];
        __syncthreads();
    }
    if (tid == 0) partials[blockIdx.x] = red[0];
}

// ---------------------------------------------------------------------------
// K3: single-block sum of the 8192 per-block loss partials.  (R0 verbatim)
__global__ __launch_bounds__(256) void reduce_loss(const float* __restrict__ partials,
                                                   float* __restrict__ out) {
    const int tid = threadIdx.x;
    float s = 0.0f;
    #pragma unroll
    for (int i = 0; i < 8; i++) {
        f32x4 v = *(const f32x4*)(partials + (size_t)(i * 256 + tid) * 4);
        s += v[0] + v[1] + v[2] + v[3];
    }
    __shared__ float red[256];
    red[tid] = s;
    __syncthreads();
    #pragma unroll
    for (int st = 128; st > 0; st >>= 1) {
        if (tid < st) red[tid] += red[tid + st];
        __syncthreads();
    }
    if (tid == 0)
        out[(size_t)N_TOK * DDIM] = red[0] * (0.25f / (float)((size_t)N_TOK * DDIM));
}

// ---------------------------------------------------------------------------
extern "C" void kernel_launch(void* const* d_in, const int* in_sizes, int n_in,
                              void* d_out, int out_size, void* d_ws, size_t ws_size,
                              hipStream_t stream) {
    const float* x  = (const float*)d_in[0];
    const float* cb = (const float*)d_in[1];
    float* out = (float*)d_out;

    // ws: cb16 (4 MB f16) | cnorm[8192] | cand[32768*8] | partials[8192]
    half_t* cb16     = (half_t*)d_ws;
    float*  cnorm    = (float*)(cb16 + (size_t)KCB * DDIM);
    float*  cand     = cnorm + KCB;
    float*  partials = cand + (size_t)N_TOK * 8;

    prep_cb<<<KCB, 64, 0, stream>>>(cb, cb16, cnorm);
    dim3 gA(N_TOK / 256, SLICES);
    passA<<<gA, 256, 0, stream>>>(x, cb16, cnorm, cand);
    finalize_kernel<<<NFBLK, 256, 0, stream>>>(x, cb, cnorm, cand, out, partials);
    reduce_loss<<<1, 256, 0, stream>>>(partials, out);
}